// Round 3
// baseline (622.394 us; speedup 1.0000x reference)
//
#include <hip/hip_runtime.h>

#define HEADS 16
#define SEQL 32
#define HD 64
#define PASTN 32768
#define TOTN 32800
#define NE 1024
#define CHUNK 1024     // keys per past chunk
#define NPC 32         // number of past chunks
#define NCHUNK 33      // 32 past chunks + 1 new-key chunk
#define KT 64          // keys per LDS tile
#define LDP 68         // LDS leading dim: 68%32=4 -> rows shift 4 banks/row
#define NEGV -10000.0f

// ---------------- kernel 1: qkv = x @ w_attn + b_attn ----------------
__global__ __launch_bounds__(256) void qkv_kernel(
    const float* __restrict__ x, const float* __restrict__ w,
    const float* __restrict__ b, float* __restrict__ qws,
    float* __restrict__ present)
{
    int idx = blockIdx.x * 256 + threadIdx.x;      // 32*3072 = 98304
    int s = idx / 3072;
    int col = idx - s * 3072;
    const float4* x4 = (const float4*)(x + s * NE);
    float a0 = 0.f, a1 = 0.f, a2 = 0.f, a3 = 0.f;
#pragma unroll 8
    for (int k4 = 0; k4 < NE / 4; ++k4) {
        float4 xv = x4[k4];
        const float* wp = w + (k4 * 4) * 3072 + col;
        a0 = fmaf(xv.x, wp[0],        a0);
        a1 = fmaf(xv.y, wp[3072],     a1);
        a2 = fmaf(xv.z, wp[2 * 3072], a2);
        a3 = fmaf(xv.w, wp[3 * 3072], a3);
    }
    float acc = b[col] + ((a0 + a1) + (a2 + a3));
    int g = col >> 10;          // 0=q, 1=k, 2=v
    int e = col & 1023;
    int h = e >> 6, d = e & 63;
    if (g == 0)
        qws[(h * SEQL + s) * HD + d] = acc;
    else
        present[(((g - 1) * HEADS + h) * TOTN + PASTN + s) * HD + d] = acc;
}

// ------- fused scores+softmax+PV for one K/V tile (threads 0..127) -------
// Thread (qg,lg): scores for q rows qg*4..+3, keys {lg,lg+16,..}; softmax
// row-reduce via 16-lane shfl groups; m/l/alpha live in registers (the PV
// thread for a q-row IS its scores thread). Only p goes through LDS (Ss),
// and the scores->PV handoff is intra-wave: wave0 owns q0..15, wave1 owns
// q16..31, so s_waitcnt lgkmcnt(0) suffices (no block barrier).
template<int NT, bool MASK>
__device__ __forceinline__ void compute_tile(
    float (&Qs)[SEQL][LDP], float (&Ks)[KT][LDP],
    float (&Vs)[KT][LDP], float (&Ss)[SEQL][LDP],
    int qg, int lg, float4 (&acc4)[4], float (&mreg)[4], float (&lreg)[4])
{
    constexpr int NU = NT / 16;
    float s[4][NU];
#pragma unroll
    for (int j = 0; j < 4; ++j)
#pragma unroll
        for (int u = 0; u < NU; ++u) s[j][u] = 0.f;
#pragma unroll
    for (int d4 = 0; d4 < 16; ++d4) {
        float4 qv[4], kv[NU];
#pragma unroll
        for (int j = 0; j < 4; ++j)
            qv[j] = *(const float4*)&Qs[qg * 4 + j][d4 * 4];
#pragma unroll
        for (int u = 0; u < NU; ++u)
            kv[u] = *(const float4*)&Ks[lg + u * 16][d4 * 4];
#pragma unroll
        for (int j = 0; j < 4; ++j)
#pragma unroll
            for (int u = 0; u < NU; ++u) {
                s[j][u] = fmaf(qv[j].x, kv[u].x, s[j][u]);
                s[j][u] = fmaf(qv[j].y, kv[u].y, s[j][u]);
                s[j][u] = fmaf(qv[j].z, kv[u].z, s[j][u]);
                s[j][u] = fmaf(qv[j].w, kv[u].w, s[j][u]);
            }
    }
    float alpha[4];
#pragma unroll
    for (int j = 0; j < 4; ++j) {
        int q = qg * 4 + j;
        float mt = -3e38f;
#pragma unroll
        for (int u = 0; u < NU; ++u) {
            float sv = s[j][u] * 0.125f;          // 1/sqrt(64)
            if (MASK && (lg + 16 * u) > q) sv = NEGV;
            s[j][u] = sv;
            mt = fmaxf(mt, sv);
        }
        mt = fmaxf(mt, __shfl_xor(mt, 1));
        mt = fmaxf(mt, __shfl_xor(mt, 2));
        mt = fmaxf(mt, __shfl_xor(mt, 4));
        mt = fmaxf(mt, __shfl_xor(mt, 8));
        float mnew = fmaxf(mreg[j], mt);
        alpha[j] = __expf(mreg[j] - mnew);
        mreg[j] = mnew;
        float ps = 0.f;
#pragma unroll
        for (int u = 0; u < NU; ++u) {
            float p = __expf(s[j][u] - mnew);
            Ss[q][lg + 16 * u] = p;
            ps += p;
        }
        ps += __shfl_xor(ps, 1);
        ps += __shfl_xor(ps, 2);
        ps += __shfl_xor(ps, 4);
        ps += __shfl_xor(ps, 8);
        lreg[j] = lreg[j] * alpha[j] + ps;
    }
    // make this wave's Ss writes visible to all its lanes before PV reads
    asm volatile("s_waitcnt lgkmcnt(0)" ::: "memory");
#pragma unroll
    for (int j = 0; j < 4; ++j) {
        acc4[j].x *= alpha[j]; acc4[j].y *= alpha[j];
        acc4[j].z *= alpha[j]; acc4[j].w *= alpha[j];
    }
#pragma unroll
    for (int t4 = 0; t4 < NT / 4; ++t4) {
        float4 vvv[4];
#pragma unroll
        for (int u = 0; u < 4; ++u)
            vvv[u] = *(const float4*)&Vs[t4 * 4 + u][lg * 4];
#pragma unroll
        for (int j = 0; j < 4; ++j) {
            float4 p = *(const float4*)&Ss[qg * 4 + j][t4 * 4];
            acc4[j].x = fmaf(p.x, vvv[0].x, acc4[j].x);
            acc4[j].x = fmaf(p.y, vvv[1].x, acc4[j].x);
            acc4[j].x = fmaf(p.z, vvv[2].x, acc4[j].x);
            acc4[j].x = fmaf(p.w, vvv[3].x, acc4[j].x);
            acc4[j].y = fmaf(p.x, vvv[0].y, acc4[j].y);
            acc4[j].y = fmaf(p.y, vvv[1].y, acc4[j].y);
            acc4[j].y = fmaf(p.z, vvv[2].y, acc4[j].y);
            acc4[j].y = fmaf(p.w, vvv[3].y, acc4[j].y);
            acc4[j].z = fmaf(p.x, vvv[0].z, acc4[j].z);
            acc4[j].z = fmaf(p.y, vvv[1].z, acc4[j].z);
            acc4[j].z = fmaf(p.z, vvv[2].z, acc4[j].z);
            acc4[j].z = fmaf(p.w, vvv[3].z, acc4[j].z);
            acc4[j].w = fmaf(p.x, vvv[0].w, acc4[j].w);
            acc4[j].w = fmaf(p.y, vvv[1].w, acc4[j].w);
            acc4[j].w = fmaf(p.z, vvv[2].w, acc4[j].w);
            acc4[j].w = fmaf(p.w, vvv[3].w, acc4[j].w);
        }
    }
}

// ------- kernel 2: fused cache-copy + flash-decode partials -------
// Register-prefetch double buffer: tile t+1's global loads issue before
// tile t's compute; regs drain to LDS+present after the compute barrier.
// 2 barriers per tile (was 4).
__global__ __launch_bounds__(256, 2) void attn_partial(
    const float* __restrict__ past, const float* __restrict__ qws,
    float* __restrict__ present, float* __restrict__ opart,
    float* __restrict__ mws, float* __restrict__ lws)
{
    int h = blockIdx.x / NCHUNK;
    int c = blockIdx.x - h * NCHUNK;
    __shared__ __align__(16) float Qs[SEQL][LDP];   // 8.5 KB
    __shared__ __align__(16) float Ks[KT][LDP];     // 17 KB
    __shared__ __align__(16) float Vs[KT][LDP];     // 17 KB
    __shared__ __align__(16) float Ss[SEQL][LDP];   // 8.5 KB
    int tid = threadIdx.x;

    // stage Q
    for (int i = tid; i < SEQL * 16; i += 256) {
        int q = i >> 4, s4i = i & 15;
        *(float4*)&Qs[q][s4i * 4] = *(const float4*)&qws[(h * SEQL + q) * HD + s4i * 4];
    }

    float4 acc4[4];
    float mreg[4], lreg[4];
#pragma unroll
    for (int j = 0; j < 4; ++j) {
        acc4[j] = make_float4(0.f, 0.f, 0.f, 0.f);
        mreg[j] = -3e38f;
        lreg[j] = 0.f;
    }
    int qg = tid >> 4;   // compute threads (tid<128): 0..7
    int lg = tid & 15;

    if (c < NPC) {
        int kstart = c * CHUNK;
        int row = tid >> 4;     // staging: rows row, row+16, row+32, row+48
        int s4 = tid & 15;
        float4 kk[4], vv[4];

        auto loadT = [&](int t0) {
#pragma unroll
            for (int r = 0; r < 4; ++r) {
                int grow = kstart + t0 + row + r * 16;
                kk[r] = *(const float4*)&past[(h * PASTN + grow) * HD + s4 * 4];
                vv[r] = *(const float4*)&past[((HEADS + h) * PASTN + grow) * HD + s4 * 4];
            }
        };
        auto writeT = [&](int t0) {
#pragma unroll
            for (int r = 0; r < 4; ++r) {
                int grow = kstart + t0 + row + r * 16;
                *(float4*)&present[(h * TOTN + grow) * HD + s4 * 4] = kk[r];
                *(float4*)&present[((HEADS + h) * TOTN + grow) * HD + s4 * 4] = vv[r];
                *(float4*)&Ks[row + r * 16][s4 * 4] = kk[r];
                *(float4*)&Vs[row + r * 16][s4 * 4] = vv[r];
            }
        };

        loadT(0);
        __syncthreads();           // Q staged
        writeT(0);
        __syncthreads();           // tile 0 visible
        for (int t0 = 0; t0 < CHUNK; t0 += KT) {
            bool pf = (t0 + KT) < CHUNK;
            if (pf) loadT(t0 + KT);            // prefetch under compute
            if (tid < 128)
                compute_tile<KT, false>(Qs, Ks, Vs, Ss, qg, lg, acc4, mreg, lreg);
            if (pf) {
                __syncthreads();               // compute done with Ks/Vs
                writeT(t0 + KT);
                __syncthreads();               // next tile visible
            }
        }
    } else {
        // new-keys chunk: 32 keys from present (written by qkv_kernel)
        int row = tid >> 4;
        int s4 = tid & 15;
#pragma unroll
        for (int r = 0; r < 2; ++r) {
            int rw = row + r * 16;
            int grow = PASTN + rw;
            *(float4*)&Ks[rw][s4 * 4] = *(const float4*)&present[(h * TOTN + grow) * HD + s4 * 4];
            *(float4*)&Vs[rw][s4 * 4] = *(const float4*)&present[((HEADS + h) * TOTN + grow) * HD + s4 * 4];
        }
        __syncthreads();
        if (tid < 128)
            compute_tile<SEQL, true>(Qs, Ks, Vs, Ss, qg, lg, acc4, mreg, lreg);
    }

    // ---- write partials ----
    if (tid < 128) {
        if (lg == 0) {
#pragma unroll
            for (int j = 0; j < 4; ++j) {
                mws[(h * NCHUNK + c) * SEQL + qg * 4 + j] = mreg[j];
                lws[(h * NCHUNK + c) * SEQL + qg * 4 + j] = lreg[j];
            }
        }
#pragma unroll
        for (int j = 0; j < 4; ++j)
            *(float4*)&opart[((h * NCHUNK + c) * SEQL + qg * 4 + j) * HD + lg * 4] = acc4[j];
    }
}

// -------- kernel 3: combine chunk partials, merge heads --------
__global__ __launch_bounds__(64) void attn_reduce(
    const float* __restrict__ opart, const float* __restrict__ mws,
    const float* __restrict__ lws, float* __restrict__ aws)
{
    int h = blockIdx.x >> 5;
    int q = blockIdx.x & 31;
    int d = threadIdx.x;
    float M = -3e38f;
    for (int c = 0; c < NCHUNK; ++c)
        M = fmaxf(M, mws[(h * NCHUNK + c) * SEQL + q]);
    float L = 0.f, o = 0.f;
    for (int c = 0; c < NCHUNK; ++c) {
        float wgt = __expf(mws[(h * NCHUNK + c) * SEQL + q] - M);
        L = fmaf(lws[(h * NCHUNK + c) * SEQL + q], wgt, L);
        o = fmaf(opart[((h * NCHUNK + c) * SEQL + q) * HD + d], wgt, o);
    }
    aws[q * NE + h * HD + d] = o / L;   // merged heads: [s][e]
}

// -------- kernel 4: out = a @ w_proj + b_proj --------
__global__ __launch_bounds__(256) void proj_kernel(
    const float* __restrict__ aws, const float* __restrict__ w,
    const float* __restrict__ b, float* __restrict__ out)
{
    int idx = blockIdx.x * 256 + threadIdx.x;   // 32*1024
    int s = idx >> 10, e = idx & 1023;
    const float4* a4 = (const float4*)(aws + s * NE);
    float a0 = 0.f, a1 = 0.f, a2 = 0.f, a3 = 0.f;
#pragma unroll 8
    for (int k4 = 0; k4 < NE / 4; ++k4) {
        float4 xv = a4[k4];
        const float* wp = w + (k4 * 4) * NE + e;
        a0 = fmaf(xv.x, wp[0],      a0);
        a1 = fmaf(xv.y, wp[NE],     a1);
        a2 = fmaf(xv.z, wp[2 * NE], a2);
        a3 = fmaf(xv.w, wp[3 * NE], a3);
    }
    out[idx] = b[e] + ((a0 + a1) + (a2 + a3));
}

extern "C" void kernel_launch(void* const* d_in, const int* in_sizes, int n_in,
                              void* d_out, int out_size, void* d_ws, size_t ws_size,
                              hipStream_t stream) {
    const float* x      = (const float*)d_in[0];
    const float* past   = (const float*)d_in[1];   // [2,16,32768,64]
    const float* w_attn = (const float*)d_in[2];   // [1024,3072]
    const float* b_attn = (const float*)d_in[3];
    const float* w_proj = (const float*)d_in[4];   // [1024,1024]
    const float* b_proj = (const float*)d_in[5];

    float* out     = (float*)d_out;                 // [32,1024]
    float* present = out + SEQL * NE;               // [2,16,32800,64]

    // workspace layout (floats)
    float* wsf   = (float*)d_ws;
    float* qws   = wsf;                     // 16*32*64      = 32768
    float* aws   = wsf + 32768;             // 32*1024       = 32768
    float* mws   = wsf + 65536;             // 16*33*32      = 16896
    float* lws   = mws + 16896;             // 16896
    float* opart = lws + 16896;             // 16*33*32*64   = 1081344

    qkv_kernel<<<(SEQL * 3072) / 256, 256, 0, stream>>>(x, w_attn, b_attn, qws, present);
    attn_partial<<<HEADS * NCHUNK, 256, 0, stream>>>(past, qws, present, opart, mws, lws);
    attn_reduce<<<HEADS * SEQL, 64, 0, stream>>>(opart, mws, lws, aws);
    proj_kernel<<<(SEQL * NE) / 256, 256, 0, stream>>>(aws, w_proj, b_proj, out);
}